// Round 2
// baseline (261.638 us; speedup 1.0000x reference)
//
#include <hip/hip_runtime.h>
#include <hip/hip_bf16.h>
#include <stdint.h>

// Problem constants (DynamicConv1dTBC): T=2048 B=8 C=1024 H=16 K=7 pad_l=6
#define T_DIM 2048
#define B_DIM 8
#define C_DIM 1024
#define H_DIM 16
#define K_DIM 7
#define M_DIM (T_DIM * B_DIM)   // 16384 rows when flattened (t*B + b)
#define NLOG 144                // H*K (112) + 2H (32) logit columns

typedef __attribute__((ext_vector_type(8))) short short8;   // 8 bf16 = one MFMA A/B frag
typedef __attribute__((ext_vector_type(4))) float floatx4;  // MFMA C/D frag

__device__ __forceinline__ float bf2f(uint32_t u) {
    union { uint32_t i; float f; } v; v.i = u << 16; return v.f;
}
__device__ __forceinline__ ushort f2bf(float f) {
    __hip_bfloat16 h = __float2bfloat16(f);
    return *(ushort*)&h;
}

// ---------------------------------------------------------------------------
// Kernel D: fp32 -> bf16 downcast of x, [w_weight;glu_w] (144 rows), out_w.
// One grid-stride-free flat launch; 4 fp32 per thread. Region sizes are all
// multiples of 4 so a float4 never straddles regions.
// ---------------------------------------------------------------------------
#define S_X  ((size_t)M_DIM * C_DIM)        // 16,777,216
#define S_W  ((size_t)112 * C_DIM)          // 114,688
#define S_G  ((size_t)32 * C_DIM)           // 32,768
#define S_O  ((size_t)C_DIM * C_DIM)        // 1,048,576
#define S_TOT (S_X + S_W + S_G + S_O)       // 17,973,248 (= 4 * 256 * 17552)

__global__ __launch_bounds__(256) void cvt_kernel(
    const float* __restrict__ x, const float* __restrict__ w_weight,
    const float* __restrict__ glu_w, const float* __restrict__ out_w,
    ushort* __restrict__ xb, ushort* __restrict__ wb, ushort* __restrict__ Wb)
{
    size_t gid = ((size_t)blockIdx.x * 256 + threadIdx.x) * 4;
    const float* src; ushort* dst; size_t off;
    if (gid < S_X)                   { src = x;        dst = xb;        off = gid; }
    else if (gid < S_X + S_W)        { src = w_weight; dst = wb;        off = gid - S_X; }
    else if (gid < S_X + S_W + S_G)  { src = glu_w;    dst = wb + S_W;  off = gid - S_X - S_W; }
    else                             { src = out_w;    dst = Wb;        off = gid - S_X - S_W - S_G; }
    float4 v = *(const float4*)(src + off);
    ushort4 o; o.x = f2bf(v.x); o.y = f2bf(v.y); o.z = f2bf(v.z); o.w = f2bf(v.w);
    *(ushort4*)(dst + off) = o;
}

// ---------------------------------------------------------------------------
// Kernel A: logits[m, n] = xb[m,:] . wb[n,:]  for n in [0,144)
// MFMA 16x16x32 bf16; A/B frags loaded directly from global (wb L2-resident).
// One wave per 16-row m-tile; 9 n-tiles.
// ---------------------------------------------------------------------------
__global__ __launch_bounds__(256) void logits_kernel(
    const ushort* __restrict__ xb,   // (M, C) bf16
    const ushort* __restrict__ wb,   // (144, C) bf16
    float* __restrict__ logits)      // (M, 144) fp32
{
    const int wave = threadIdx.x >> 6;
    const int lane = threadIdx.x & 63;
    const int m0 = (blockIdx.x * 4 + wave) * 16;
    const int fr = lane & 15;
    const int q  = lane >> 4;

    floatx4 acc[9];
#pragma unroll
    for (int j = 0; j < 9; ++j) acc[j] = (floatx4){0.f, 0.f, 0.f, 0.f};

    const ushort* arow = xb + (size_t)(m0 + fr) * C_DIM + q * 8;
    const ushort* brow = wb + (size_t)fr * C_DIM + q * 8;   // + j*16*C per n-tile

    for (int k0 = 0; k0 < C_DIM; k0 += 32) {
        short8 a = *(const short8*)(arow + k0);
#pragma unroll
        for (int j = 0; j < 9; ++j) {
            short8 b = *(const short8*)(brow + (size_t)j * 16 * C_DIM + k0);
            acc[j] = __builtin_amdgcn_mfma_f32_16x16x32_bf16(a, b, acc[j], 0, 0, 0);
        }
    }

    // D layout: col = lane&15, row = q*4 + r
#pragma unroll
    for (int j = 0; j < 9; ++j) {
        int n = j * 16 + fr;
#pragma unroll
        for (int r = 0; r < 4; ++r) {
            int m = m0 + q * 4 + r;
            logits[(size_t)m * NLOG + n] = acc[j][r];
        }
    }
}

// ---------------------------------------------------------------------------
// Kernel B: per (t,b): softmax over K per head, GLU gate, depthwise dynamic
// conv over K taps, write gated conv output y (bf16).
// One 64-lane wave per (t,b). Lane L handles channels [16L, 16L+16).
// ---------------------------------------------------------------------------
__global__ __launch_bounds__(64) void conv_kernel(
    const ushort* __restrict__ xb,       // (T,B,C) bf16
    const float* __restrict__ logits,    // (M,144) fp32
    const float* __restrict__ glu_b,     // (2H,) fp32
    const int* __restrict__ padding_l_,  // scalar
    ushort* __restrict__ y)              // (T,B,C) bf16
{
    const int tb = blockIdx.x;
    const int t = tb / B_DIM, b = tb % B_DIM;
    const int lane = threadIdx.x;
    const int pad = *padding_l_;

    __shared__ float wsm[H_DIM][K_DIM];
    __shared__ float gsm[H_DIM];

    if (lane < H_DIM) {
        const float* lg = logits + (size_t)tb * NLOG;
        float l0[K_DIM];
        float mx = -1e30f;
#pragma unroll
        for (int k = 0; k < K_DIM; ++k) { l0[k] = lg[lane * K_DIM + k]; mx = fmaxf(mx, l0[k]); }
        float s = 0.f;
#pragma unroll
        for (int k = 0; k < K_DIM; ++k) { l0[k] = __expf(l0[k] - mx); s += l0[k]; }
        float inv = 1.f / s;
#pragma unroll
        for (int k = 0; k < K_DIM; ++k) wsm[lane][k] = l0[k] * inv;
        float ga = lg[112 + 2 * lane]     + glu_b[2 * lane];
        float gb = lg[112 + 2 * lane + 1] + glu_b[2 * lane + 1];
        gsm[lane] = ga * (1.f / (1.f + __expf(-gb)));
    }
    __syncthreads();

    const int c0 = lane * 16;
    const int h = lane >> 2;   // c0/64
    float accv[16];
#pragma unroll
    for (int i = 0; i < 16; ++i) accv[i] = 0.f;

    for (int k = 0; k < K_DIM; ++k) {
        int ts = t + k - pad;
        if (ts < 0 || ts >= T_DIM) continue;
        float wk = wsm[h][k];
        const uint4* xp = (const uint4*)(xb + ((size_t)ts * B_DIM + b) * C_DIM + c0);
        uint4 v0 = xp[0], v1 = xp[1];
        uint32_t u[8] = {v0.x, v0.y, v0.z, v0.w, v1.x, v1.y, v1.z, v1.w};
#pragma unroll
        for (int i = 0; i < 8; ++i) {
            accv[2 * i]     += wk * bf2f(u[i] & 0xffffu);
            accv[2 * i + 1] += wk * bf2f(u[i] >> 16);
        }
    }

    float g = gsm[h];
    uint32_t o[8];
#pragma unroll
    for (int i = 0; i < 8; ++i) {
        o[i] = (uint32_t)f2bf(accv[2 * i] * g) | ((uint32_t)f2bf(accv[2 * i + 1] * g) << 16);
    }
    uint4* yr = (uint4*)(y + (size_t)tb * C_DIM + c0);
    yr[0] = (uint4){o[0], o[1], o[2], o[3]};
    yr[1] = (uint4){o[4], o[5], o[6], o[7]};
}

// ---------------------------------------------------------------------------
// Kernel C: out[m,n] = sum_k y[m,k] * Wb[n,k] + out_b[n]  (bf16 MFMA, fp32 out)
// m97-structure: 128x128 tile, BK=64, global_load_lds width-16 staging,
// 4 waves each owning a 64x64 subtile = 4x4 grid of 16x16x32 MFMAs.
// ---------------------------------------------------------------------------
__global__ __launch_bounds__(256) void out_gemm(
    const ushort* __restrict__ y,     // (M, C) bf16
    const ushort* __restrict__ Wb,    // (C, C) bf16, out col n uses row n
    const float* __restrict__ bias,   // (C,) fp32
    float* __restrict__ out)          // (M, C) fp32
{
    __shared__ __align__(16) ushort As[128 * 64];
    __shared__ __align__(16) ushort Bs[128 * 64];

    const int bn = blockIdx.x & 7;       // N/128 = 8
    const int bm = blockIdx.x >> 3;      // M/128 = 128
    const int m0 = bm * 128, n0 = bn * 128;
    const int tid = threadIdx.x;
    const int lane = tid & 63, wave = tid >> 6;
    const int wm = (wave >> 1) * 64, wn = (wave & 1) * 64;
    const int fr = lane & 15, q = lane >> 4;

    floatx4 acc[4][4];
#pragma unroll
    for (int i = 0; i < 4; ++i)
#pragma unroll
        for (int j = 0; j < 4; ++j) acc[i][j] = (floatx4){0.f, 0.f, 0.f, 0.f};

    for (int k0 = 0; k0 < C_DIM; k0 += 64) {
        __syncthreads();   // previous compute done before LDS overwrite
#pragma unroll
        for (int j = 0; j < 4; ++j) {
            int idx = j * 256 + tid;         // 16B chunk index in [0,1024)
            int r = idx >> 3, ch = idx & 7;  // row in tile, 16B chunk in row
            const ushort* ga = y + (size_t)(m0 + r) * C_DIM + k0 + ch * 8;
            __builtin_amdgcn_global_load_lds(
                (const __attribute__((address_space(1))) void*)ga,
                (__attribute__((address_space(3))) void*)(As + idx * 8), 16, 0, 0);
            const ushort* gb = Wb + (size_t)(n0 + r) * C_DIM + k0 + ch * 8;
            __builtin_amdgcn_global_load_lds(
                (const __attribute__((address_space(1))) void*)gb,
                (__attribute__((address_space(3))) void*)(Bs + idx * 8), 16, 0, 0);
        }
        __syncthreads();   // drains vmcnt (global_load_lds) before reads

#pragma unroll
        for (int s = 0; s < 64; s += 32) {
            short8 a[4], b[4];
#pragma unroll
            for (int i = 0; i < 4; ++i)
                a[i] = *(const short8*)(As + (wm + i * 16 + fr) * 64 + s + q * 8);
#pragma unroll
            for (int j = 0; j < 4; ++j)
                b[j] = *(const short8*)(Bs + (wn + j * 16 + fr) * 64 + s + q * 8);
#pragma unroll
            for (int i = 0; i < 4; ++i)
#pragma unroll
                for (int j = 0; j < 4; ++j)
                    acc[i][j] = __builtin_amdgcn_mfma_f32_16x16x32_bf16(a[i], b[j], acc[i][j], 0, 0, 0);
        }
    }

#pragma unroll
    for (int j = 0; j < 4; ++j) {
        int n = n0 + wn + j * 16 + fr;
        float bv = bias[n];
#pragma unroll
        for (int i = 0; i < 4; ++i) {
#pragma unroll
            for (int r = 0; r < 4; ++r) {
                int m = m0 + wm + i * 16 + q * 4 + r;
                out[(size_t)m * C_DIM + n] = acc[i][j][r] + bv;
            }
        }
    }
}

// ---------------------------------------------------------------------------
extern "C" void kernel_launch(void* const* d_in, const int* in_sizes, int n_in,
                              void* d_out, int out_size, void* d_ws, size_t ws_size,
                              hipStream_t stream) {
    const float* x        = (const float*)d_in[0];
    const float* w_weight = (const float*)d_in[1];
    const float* glu_w    = (const float*)d_in[2];
    const float* glu_b    = (const float*)d_in[3];
    const float* out_w    = (const float*)d_in[4];
    const float* out_b    = (const float*)d_in[5];
    const int* padding_l  = (const int*)d_in[6];
    float* out = (float*)d_out;

    char* ws = (char*)d_ws;
    ushort* xb    = (ushort*)ws;                                  // M*C bf16   (33.5 MB)
    ushort* y     = xb + S_X;                                     // M*C bf16   (33.5 MB)
    ushort* wb    = y + S_X;                                      // 144*C bf16 (0.3 MB)
    ushort* Wb    = wb + S_W + S_G;                               // C*C bf16   (2.1 MB)
    float* logits = (float*)(Wb + S_O);                           // M*144 fp32 (9.4 MB)

    cvt_kernel<<<(S_TOT / 4 + 255) / 256, 256, 0, stream>>>(x, w_weight, glu_w, out_w, xb, wb, Wb);
    logits_kernel<<<M_DIM / 64, 256, 0, stream>>>(xb, wb, logits);
    conv_kernel<<<M_DIM, 64, 0, stream>>>(xb, logits, glu_b, padding_l, y);
    out_gemm<<<(M_DIM / 128) * (C_DIM / 128), 256, 0, stream>>>(y, Wb, out_b, out);
}

// Round 3
// 244.596 us; speedup vs baseline: 1.0697x; 1.0697x over previous
//
#include <hip/hip_runtime.h>
#include <hip/hip_bf16.h>
#include <stdint.h>

// Problem constants (DynamicConv1dTBC): T=2048 B=8 C=1024 H=16 K=7 pad_l=6
#define T_DIM 2048
#define B_DIM 8
#define C_DIM 1024
#define H_DIM 16
#define K_DIM 7
#define M_DIM (T_DIM * B_DIM)   // 16384 rows (m = t*B + b)
#define NLOG 144                // H*K (112) + 2H (32) logit columns

typedef __attribute__((ext_vector_type(8))) short short8;
typedef __attribute__((ext_vector_type(4))) float floatx4;

__device__ __forceinline__ ushort f2bf(float f) {
    __hip_bfloat16 h = __float2bfloat16(f);
    return *(ushort*)&h;
}

// ---------------------------------------------------------------------------
// Kernel W: fp32 -> bf16 downcast of weights only: [w_weight;glu_w] -> wb
// (144 x 1024) and out_w -> Wb (1024 x 1024).  1,196,032 elements total.
// ---------------------------------------------------------------------------
#define S_W  ((size_t)112 * C_DIM)          // 114,688
#define S_G  ((size_t)32 * C_DIM)           // 32,768
#define S_O  ((size_t)C_DIM * C_DIM)        // 1,048,576
#define S_WG (S_W + S_G)                    // 147,456
#define S_CVT (S_WG + S_O)                  // 1,196,032 = 4*256*1168

__global__ __launch_bounds__(256) void cvt_w_kernel(
    const float* __restrict__ w_weight, const float* __restrict__ glu_w,
    const float* __restrict__ out_w,
    ushort* __restrict__ wb, ushort* __restrict__ Wb)
{
    size_t gid = ((size_t)blockIdx.x * 256 + threadIdx.x) * 4;
    const float* src; ushort* dst; size_t off;
    if (gid < S_W)            { src = w_weight; dst = wb;       off = gid; }
    else if (gid < S_WG)      { src = glu_w;    dst = wb + S_W; off = gid - S_W; }
    else                      { src = out_w;    dst = Wb;       off = gid - S_WG; }
    float4 v = *(const float4*)(src + off);
    ushort4 o; o.x = f2bf(v.x); o.y = f2bf(v.y); o.z = f2bf(v.z); o.w = f2bf(v.w);
    *(ushort4*)(dst + off) = o;
}

// ---------------------------------------------------------------------------
// Kernel F (fused): per block = 16 m-rows (2 timesteps x 8 batch).
//  Phase 1: logits = x . wb^T via MFMA, K=1024 split across 4 waves (256 each),
//           fp32 x loaded directly and converted to bf16 in-register.
//  Phase 2: LDS reduction of 4 partials; softmax over K per head + GLU gate.
//  Phase 3: depthwise dynamic conv (fp32 x, 7 taps), gate, write y bf16.
// ---------------------------------------------------------------------------
__global__ __launch_bounds__(256) void fused_logits_conv(
    const float* __restrict__ x,        // (M, C) fp32
    const ushort* __restrict__ wb,      // (144, C) bf16
    const float* __restrict__ glu_b,    // (2H,) fp32
    const int* __restrict__ padding_l_, // scalar
    ushort* __restrict__ y)             // (M, C) bf16
{
    __shared__ float part[4][16][NLOG];        // 36,864 B
    __shared__ float wk[16][H_DIM][K_DIM];     //  7,168 B
    __shared__ float gg[16][H_DIM];            //  1,024 B

    const int tid = threadIdx.x;
    const int wave = tid >> 6, lane = tid & 63;
    const int fr = lane & 15, q = lane >> 4;
    const int m0 = blockIdx.x * 16;

    // ---- Phase 1: partial logits GEMM over this wave's 256-wide K-chunk ----
    floatx4 acc[9];
#pragma unroll
    for (int j = 0; j < 9; ++j) acc[j] = (floatx4){0.f, 0.f, 0.f, 0.f};

    const float* arow  = x  + (size_t)(m0 + fr) * C_DIM + wave * 256 + q * 8;
    const ushort* brow = wb + (size_t)fr * C_DIM        + wave * 256 + q * 8;

#pragma unroll
    for (int it = 0; it < 8; ++it) {
        float4 v0 = *(const float4*)(arow + it * 32);
        float4 v1 = *(const float4*)(arow + it * 32 + 4);
        short8 a;
        a[0] = (short)f2bf(v0.x); a[1] = (short)f2bf(v0.y);
        a[2] = (short)f2bf(v0.z); a[3] = (short)f2bf(v0.w);
        a[4] = (short)f2bf(v1.x); a[5] = (short)f2bf(v1.y);
        a[6] = (short)f2bf(v1.z); a[7] = (short)f2bf(v1.w);
#pragma unroll
        for (int j = 0; j < 9; ++j) {
            short8 b = *(const short8*)(brow + (size_t)j * 16 * C_DIM + it * 32);
            acc[j] = __builtin_amdgcn_mfma_f32_16x16x32_bf16(a, b, acc[j], 0, 0, 0);
        }
    }
    // D layout: col = fr, row = q*4 + r
#pragma unroll
    for (int j = 0; j < 9; ++j)
#pragma unroll
        for (int r = 0; r < 4; ++r)
            part[wave][q * 4 + r][j * 16 + fr] = acc[j][r];
    __syncthreads();

    // ---- Phase 2: reduce partials, softmax over K, GLU gate ----
    {
        const int row = tid >> 4, h = tid & 15;
        float l[K_DIM];
        float mx = -1e30f;
#pragma unroll
        for (int k = 0; k < K_DIM; ++k) {
            float s = part[0][row][h * K_DIM + k] + part[1][row][h * K_DIM + k]
                    + part[2][row][h * K_DIM + k] + part[3][row][h * K_DIM + k];
            l[k] = s; mx = fmaxf(mx, s);
        }
        float s = 0.f;
#pragma unroll
        for (int k = 0; k < K_DIM; ++k) { l[k] = __expf(l[k] - mx); s += l[k]; }
        float inv = 1.f / s;
#pragma unroll
        for (int k = 0; k < K_DIM; ++k) wk[row][h][k] = l[k] * inv;
        float ga = part[0][row][112 + 2 * h] + part[1][row][112 + 2 * h]
                 + part[2][row][112 + 2 * h] + part[3][row][112 + 2 * h] + glu_b[2 * h];
        float gb = part[0][row][113 + 2 * h] + part[1][row][113 + 2 * h]
                 + part[2][row][113 + 2 * h] + part[3][row][113 + 2 * h] + glu_b[2 * h + 1];
        gg[row][h] = ga * (1.f / (1.f + __expf(-gb)));
    }
    __syncthreads();

    // ---- Phase 3: depthwise dynamic conv + gate, write y bf16 ----
    const int pad = *padding_l_;
    const int c0 = lane * 16;
    const int h = lane >> 2;    // c0 / 64
    for (int rr = wave; rr < 16; rr += 4) {
        const int m = m0 + rr;
        const int t = m >> 3;
        float av[16];
#pragma unroll
        for (int i = 0; i < 16; ++i) av[i] = 0.f;
#pragma unroll
        for (int k = 0; k < K_DIM; ++k) {
            int ts = t + k - pad;
            if (ts < 0 || ts >= T_DIM) continue;
            float wv = wk[rr][h][k];
            const float4* xp = (const float4*)(x + ((size_t)m + 8 * (k - pad)) * C_DIM + c0);
            float4 u0 = xp[0], u1 = xp[1], u2 = xp[2], u3 = xp[3];
            av[0]  += wv * u0.x; av[1]  += wv * u0.y; av[2]  += wv * u0.z; av[3]  += wv * u0.w;
            av[4]  += wv * u1.x; av[5]  += wv * u1.y; av[6]  += wv * u1.z; av[7]  += wv * u1.w;
            av[8]  += wv * u2.x; av[9]  += wv * u2.y; av[10] += wv * u2.z; av[11] += wv * u2.w;
            av[12] += wv * u3.x; av[13] += wv * u3.y; av[14] += wv * u3.z; av[15] += wv * u3.w;
        }
        float g = gg[rr][h];
        uint32_t o[8];
#pragma unroll
        for (int i = 0; i < 8; ++i)
            o[i] = (uint32_t)f2bf(av[2 * i] * g) | ((uint32_t)f2bf(av[2 * i + 1] * g) << 16);
        uint4* yr = (uint4*)(y + (size_t)m * C_DIM + c0);
        yr[0] = (uint4){o[0], o[1], o[2], o[3]};
        yr[1] = (uint4){o[4], o[5], o[6], o[7]};
    }
}

// ---------------------------------------------------------------------------
// Kernel C: out[m,n] = sum_k y[m,k] * Wb[n,k] + out_b[n]  (bf16 MFMA, fp32 out)
// 128x128 tile, BK=64, global_load_lds width-16 staging with XOR chunk
// swizzle (kills ds_read_b128 bank conflicts), XCD-friendly block mapping.
// ---------------------------------------------------------------------------
__global__ __launch_bounds__(256) void out_gemm(
    const ushort* __restrict__ y,     // (M, C) bf16
    const ushort* __restrict__ Wb,    // (C, C) bf16
    const float* __restrict__ bias,   // (C,) fp32
    float* __restrict__ out)          // (M, C) fp32
{
    __shared__ __align__(16) ushort As[128 * 64];
    __shared__ __align__(16) ushort Bs[128 * 64];

    // bm = low bits: the 8 blocks sharing a y-tile are 128 apart -> same XCD.
    const int bm = blockIdx.x & 127;     // M/128 = 128
    const int bn = blockIdx.x >> 7;      // N/128 = 8
    const int m0 = bm * 128, n0 = bn * 128;
    const int tid = threadIdx.x;
    const int lane = tid & 63, wave = tid >> 6;
    const int wm = (wave >> 1) * 64, wn = (wave & 1) * 64;
    const int fr = lane & 15, q = lane >> 4;

    floatx4 acc[4][4];
#pragma unroll
    for (int i = 0; i < 4; ++i)
#pragma unroll
        for (int j = 0; j < 4; ++j) acc[i][j] = (floatx4){0.f, 0.f, 0.f, 0.f};

    for (int k0 = 0; k0 < C_DIM; k0 += 64) {
        __syncthreads();
#pragma unroll
        for (int j = 0; j < 4; ++j) {
            int idx = j * 256 + tid;          // LDS 16B-slot index [0,1024)
            int r = idx >> 3, cl = idx & 7;   // row, LDS chunk
            int ch = cl ^ (r & 7);            // which global chunk lands here
            const ushort* ga = y + (size_t)(m0 + r) * C_DIM + k0 + ch * 8;
            __builtin_amdgcn_global_load_lds(
                (const __attribute__((address_space(1))) void*)ga,
                (__attribute__((address_space(3))) void*)(As + idx * 8), 16, 0, 0);
            const ushort* gb = Wb + (size_t)(n0 + r) * C_DIM + k0 + ch * 8;
            __builtin_amdgcn_global_load_lds(
                (const __attribute__((address_space(1))) void*)gb,
                (__attribute__((address_space(3))) void*)(Bs + idx * 8), 16, 0, 0);
        }
        __syncthreads();

#pragma unroll
        for (int s = 0; s < 64; s += 32) {
            const int cbase = (s >> 3) + q;   // global chunk this frag wants
            short8 a[4], b[4];
#pragma unroll
            for (int i = 0; i < 4; ++i) {
                int r = wm + i * 16 + fr;
                a[i] = *(const short8*)(As + r * 64 + ((cbase ^ (r & 7)) * 8));
            }
#pragma unroll
            for (int j = 0; j < 4; ++j) {
                int r = wn + j * 16 + fr;
                b[j] = *(const short8*)(Bs + r * 64 + ((cbase ^ (r & 7)) * 8));
            }
#pragma unroll
            for (int i = 0; i < 4; ++i)
#pragma unroll
                for (int j = 0; j < 4; ++j)
                    acc[i][j] = __builtin_amdgcn_mfma_f32_16x16x32_bf16(a[i], b[j], acc[i][j], 0, 0, 0);
        }
    }

#pragma unroll
    for (int j = 0; j < 4; ++j) {
        int n = n0 + wn + j * 16 + fr;
        float bv = bias[n];
#pragma unroll
        for (int i = 0; i < 4; ++i) {
#pragma unroll
            for (int r = 0; r < 4; ++r) {
                int m = m0 + wm + i * 16 + q * 4 + r;
                out[(size_t)m * C_DIM + n] = acc[i][j][r] + bv;
            }
        }
    }
}

// ---------------------------------------------------------------------------
extern "C" void kernel_launch(void* const* d_in, const int* in_sizes, int n_in,
                              void* d_out, int out_size, void* d_ws, size_t ws_size,
                              hipStream_t stream) {
    const float* x        = (const float*)d_in[0];
    const float* w_weight = (const float*)d_in[1];
    const float* glu_w    = (const float*)d_in[2];
    const float* glu_b    = (const float*)d_in[3];
    const float* out_w    = (const float*)d_in[4];
    const float* out_b    = (const float*)d_in[5];
    const int* padding_l  = (const int*)d_in[6];
    float* out = (float*)d_out;

    char* ws = (char*)d_ws;
    ushort* y  = (ushort*)ws;                 // M*C bf16   (33.5 MB)
    ushort* wb = y + (size_t)M_DIM * C_DIM;   // 144*C bf16 (0.3 MB)
    ushort* Wb = wb + S_WG;                   // C*C bf16   (2.1 MB)

    cvt_w_kernel<<<S_CVT / 4 / 256, 256, 0, stream>>>(w_weight, glu_w, out_w, wb, Wb);
    fused_logits_conv<<<M_DIM / 16, 256, 0, stream>>>(x, wb, glu_b, padding_l, y);
    out_gemm<<<(M_DIM / 128) * (C_DIM / 128), 256, 0, stream>>>(y, Wb, out_b, out);
}

// Round 4
// 230.959 us; speedup vs baseline: 1.1328x; 1.0590x over previous
//
#include <hip/hip_runtime.h>
#include <hip/hip_bf16.h>
#include <stdint.h>

// Problem constants (DynamicConv1dTBC): T=2048 B=8 C=1024 H=16 K=7 pad_l=6
#define T_DIM 2048
#define B_DIM 8
#define C_DIM 1024
#define H_DIM 16
#define K_DIM 7
#define M_DIM (T_DIM * B_DIM)   // 16384 rows (m = t*B + b)
#define NLOG 144                // H*K (112) + 2H (32) logit columns

typedef __attribute__((ext_vector_type(8))) short short8;
typedef __attribute__((ext_vector_type(4))) float floatx4;

__device__ __forceinline__ ushort f2bf(float f) {
    __hip_bfloat16 h = __float2bfloat16(f);
    return *(ushort*)&h;
}

// ---------------------------------------------------------------------------
// Kernel W: fp32 -> bf16 downcast of weights only: [w_weight;glu_w] -> wb
// (144 x 1024) and out_w -> Wb (1024 x 1024).
// ---------------------------------------------------------------------------
#define S_W  ((size_t)112 * C_DIM)          // 114,688
#define S_G  ((size_t)32 * C_DIM)           // 32,768
#define S_O  ((size_t)C_DIM * C_DIM)        // 1,048,576
#define S_WG (S_W + S_G)                    // 147,456
#define S_CVT (S_WG + S_O)                  // 1,196,032 = 4*256*1168

__global__ __launch_bounds__(256) void cvt_w_kernel(
    const float* __restrict__ w_weight, const float* __restrict__ glu_w,
    const float* __restrict__ out_w,
    ushort* __restrict__ wb, ushort* __restrict__ Wb)
{
    size_t gid = ((size_t)blockIdx.x * 256 + threadIdx.x) * 4;
    const float* src; ushort* dst; size_t off;
    if (gid < S_W)            { src = w_weight; dst = wb;       off = gid; }
    else if (gid < S_WG)      { src = glu_w;    dst = wb + S_W; off = gid - S_W; }
    else                      { src = out_w;    dst = Wb;       off = gid - S_WG; }
    float4 v = *(const float4*)(src + off);
    ushort4 o; o.x = f2bf(v.x); o.y = f2bf(v.y); o.z = f2bf(v.z); o.w = f2bf(v.w);
    *(ushort4*)(dst + off) = o;
}

// ---------------------------------------------------------------------------
// Kernel F (fused): per block = 16 m-rows (2 timesteps x 8 batch).
// XCD-swizzled so XCD k owns contiguous t-range [256k,256k+256): consecutive
// dispatch slots on an XCD process consecutive t -> 7-tap history reads hit
// that XCD's L2 (they were phase-1/phase-3 reads of the preceding slots).
// ---------------------------------------------------------------------------
__global__ __launch_bounds__(256) void fused_logits_conv(
    const float* __restrict__ x,        // (M, C) fp32
    const ushort* __restrict__ wb,      // (144, C) bf16
    const float* __restrict__ glu_b,    // (2H,) fp32
    const int* __restrict__ padding_l_, // scalar
    ushort* __restrict__ y)             // (M, C) bf16
{
    __shared__ float part[4][16][NLOG];        // 36,864 B
    __shared__ float wk[16][H_DIM][K_DIM];     //  7,168 B
    __shared__ float gg[16][H_DIM];            //  1,024 B

    const int tid = threadIdx.x;
    const int wave = tid >> 6, lane = tid & 63;
    const int fr = lane & 15, q = lane >> 4;
    // XCD-aware remap: physical p -> logical lb; XCD (p&7) gets slots in t-order
    const int lb = (blockIdx.x & 7) * 128 + (blockIdx.x >> 3);
    const int m0 = lb * 16;

    // ---- Phase 1: partial logits GEMM over this wave's 256-wide K-chunk ----
    floatx4 acc[9];
#pragma unroll
    for (int j = 0; j < 9; ++j) acc[j] = (floatx4){0.f, 0.f, 0.f, 0.f};

    const float* arow  = x  + (size_t)(m0 + fr) * C_DIM + wave * 256 + q * 8;
    const ushort* brow = wb + (size_t)fr * C_DIM        + wave * 256 + q * 8;

#pragma unroll
    for (int it = 0; it < 8; ++it) {
        float4 v0 = *(const float4*)(arow + it * 32);
        float4 v1 = *(const float4*)(arow + it * 32 + 4);
        short8 a;
        a[0] = (short)f2bf(v0.x); a[1] = (short)f2bf(v0.y);
        a[2] = (short)f2bf(v0.z); a[3] = (short)f2bf(v0.w);
        a[4] = (short)f2bf(v1.x); a[5] = (short)f2bf(v1.y);
        a[6] = (short)f2bf(v1.z); a[7] = (short)f2bf(v1.w);
#pragma unroll
        for (int j = 0; j < 9; ++j) {
            short8 b = *(const short8*)(brow + (size_t)j * 16 * C_DIM + it * 32);
            acc[j] = __builtin_amdgcn_mfma_f32_16x16x32_bf16(a, b, acc[j], 0, 0, 0);
        }
    }
    // D layout: col = fr, row = q*4 + r
#pragma unroll
    for (int j = 0; j < 9; ++j)
#pragma unroll
        for (int r = 0; r < 4; ++r)
            part[wave][q * 4 + r][j * 16 + fr] = acc[j][r];
    __syncthreads();

    // ---- Phase 2: reduce partials, softmax over K, GLU gate ----
    {
        const int row = tid >> 4, h = tid & 15;
        float l[K_DIM];
        float mx = -1e30f;
#pragma unroll
        for (int k = 0; k < K_DIM; ++k) {
            float s = part[0][row][h * K_DIM + k] + part[1][row][h * K_DIM + k]
                    + part[2][row][h * K_DIM + k] + part[3][row][h * K_DIM + k];
            l[k] = s; mx = fmaxf(mx, s);
        }
        float s = 0.f;
#pragma unroll
        for (int k = 0; k < K_DIM; ++k) { l[k] = __expf(l[k] - mx); s += l[k]; }
        float inv = 1.f / s;
#pragma unroll
        for (int k = 0; k < K_DIM; ++k) wk[row][h][k] = l[k] * inv;
        float ga = part[0][row][112 + 2 * h] + part[1][row][112 + 2 * h]
                 + part[2][row][112 + 2 * h] + part[3][row][112 + 2 * h] + glu_b[2 * h];
        float gb = part[0][row][113 + 2 * h] + part[1][row][113 + 2 * h]
                 + part[2][row][113 + 2 * h] + part[3][row][113 + 2 * h] + glu_b[2 * h + 1];
        gg[row][h] = ga * (1.f / (1.f + __expf(-gb)));
    }
    __syncthreads();

    // ---- Phase 3: depthwise dynamic conv + gate, write y bf16 ----
    const int pad = *padding_l_;
    const int c0 = lane * 16;
    const int h = lane >> 2;    // c0 / 64
    for (int rr = wave; rr < 16; rr += 4) {
        const int m = m0 + rr;
        const int t = m >> 3;
        float av[16];
#pragma unroll
        for (int i = 0; i < 16; ++i) av[i] = 0.f;
#pragma unroll
        for (int k = 0; k < K_DIM; ++k) {
            int ts = t + k - pad;
            if (ts < 0 || ts >= T_DIM) continue;
            float wv = wk[rr][h][k];
            const float4* xp = (const float4*)(x + ((size_t)m + 8 * (k - pad)) * C_DIM + c0);
            float4 u0 = xp[0], u1 = xp[1], u2 = xp[2], u3 = xp[3];
            av[0]  += wv * u0.x; av[1]  += wv * u0.y; av[2]  += wv * u0.z; av[3]  += wv * u0.w;
            av[4]  += wv * u1.x; av[5]  += wv * u1.y; av[6]  += wv * u1.z; av[7]  += wv * u1.w;
            av[8]  += wv * u2.x; av[9]  += wv * u2.y; av[10] += wv * u2.z; av[11] += wv * u2.w;
            av[12] += wv * u3.x; av[13] += wv * u3.y; av[14] += wv * u3.z; av[15] += wv * u3.w;
        }
        float g = gg[rr][h];
        uint32_t o[8];
#pragma unroll
        for (int i = 0; i < 8; ++i)
            o[i] = (uint32_t)f2bf(av[2 * i] * g) | ((uint32_t)f2bf(av[2 * i + 1] * g) << 16);
        uint4* yr = (uint4*)(y + (size_t)m * C_DIM + c0);
        yr[0] = (uint4){o[0], o[1], o[2], o[3]};
        yr[1] = (uint4){o[4], o[5], o[6], o[7]};
    }
}

// ---------------------------------------------------------------------------
// Kernel C: out[m,n] = sum_k y[m,k] * Wb[n,k] + out_b[n]  (bf16 MFMA, fp32 out)
// 128x128 tile, BK=64, global_load_lds width-16 staging with XOR chunk
// swizzle. Dispatch mapping: the 8 bn-blocks sharing an A-tile are 8
// CONSECUTIVE slots on one XCD (concurrent -> A-tile L2-reuse), and each XCD
// keeps the full 2 MB Wb hot. XCD k covers y rows [2048k, 2048k+2048) —
// the same rows fused wrote on XCD k.
// ---------------------------------------------------------------------------
__global__ __launch_bounds__(256) void out_gemm(
    const ushort* __restrict__ y,     // (M, C) bf16
    const ushort* __restrict__ Wb,    // (C, C) bf16
    const float* __restrict__ bias,   // (C,) fp32
    float* __restrict__ out)          // (M, C) fp32
{
    __shared__ __align__(16) ushort As[128 * 64];
    __shared__ __align__(16) ushort Bs[128 * 64];

    const int xcd = blockIdx.x & 7, slot = blockIdx.x >> 3;
    const int bm = xcd * 16 + (slot >> 3);   // [0,128)
    const int bn = slot & 7;                 // [0,8)
    const int m0 = bm * 128, n0 = bn * 128;
    const int tid = threadIdx.x;
    const int lane = tid & 63, wave = tid >> 6;
    const int wm = (wave >> 1) * 64, wn = (wave & 1) * 64;
    const int fr = lane & 15, q = lane >> 4;

    floatx4 acc[4][4];
#pragma unroll
    for (int i = 0; i < 4; ++i)
#pragma unroll
        for (int j = 0; j < 4; ++j) acc[i][j] = (floatx4){0.f, 0.f, 0.f, 0.f};

    for (int k0 = 0; k0 < C_DIM; k0 += 64) {
        __syncthreads();
#pragma unroll
        for (int j = 0; j < 4; ++j) {
            int idx = j * 256 + tid;          // LDS 16B-slot index [0,1024)
            int r = idx >> 3, cl = idx & 7;   // row, LDS chunk
            int ch = cl ^ (r & 7);            // which global chunk lands here
            const ushort* ga = y + (size_t)(m0 + r) * C_DIM + k0 + ch * 8;
            __builtin_amdgcn_global_load_lds(
                (const __attribute__((address_space(1))) void*)ga,
                (__attribute__((address_space(3))) void*)(As + idx * 8), 16, 0, 0);
            const ushort* gb = Wb + (size_t)(n0 + r) * C_DIM + k0 + ch * 8;
            __builtin_amdgcn_global_load_lds(
                (const __attribute__((address_space(1))) void*)gb,
                (__attribute__((address_space(3))) void*)(Bs + idx * 8), 16, 0, 0);
        }
        __syncthreads();

#pragma unroll
        for (int s = 0; s < 64; s += 32) {
            const int cbase = (s >> 3) + q;   // global chunk this frag wants
            short8 a[4], b[4];
#pragma unroll
            for (int i = 0; i < 4; ++i) {
                int r = wm + i * 16 + fr;
                a[i] = *(const short8*)(As + r * 64 + ((cbase ^ (r & 7)) * 8));
            }
#pragma unroll
            for (int j = 0; j < 4; ++j) {
                int r = wn + j * 16 + fr;
                b[j] = *(const short8*)(Bs + r * 64 + ((cbase ^ (r & 7)) * 8));
            }
#pragma unroll
            for (int i = 0; i < 4; ++i)
#pragma unroll
                for (int j = 0; j < 4; ++j)
                    acc[i][j] = __builtin_amdgcn_mfma_f32_16x16x32_bf16(a[i], b[j], acc[i][j], 0, 0, 0);
        }
    }

#pragma unroll
    for (int j = 0; j < 4; ++j) {
        int n = n0 + wn + j * 16 + fr;
        float bv = bias[n];
#pragma unroll
        for (int i = 0; i < 4; ++i) {
#pragma unroll
            for (int r = 0; r < 4; ++r) {
                int m = m0 + wm + i * 16 + q * 4 + r;
                out[(size_t)m * C_DIM + n] = acc[i][j][r] + bv;
            }
        }
    }
}

// ---------------------------------------------------------------------------
extern "C" void kernel_launch(void* const* d_in, const int* in_sizes, int n_in,
                              void* d_out, int out_size, void* d_ws, size_t ws_size,
                              hipStream_t stream) {
    const float* x        = (const float*)d_in[0];
    const float* w_weight = (const float*)d_in[1];
    const float* glu_w    = (const float*)d_in[2];
    const float* glu_b    = (const float*)d_in[3];
    const float* out_w    = (const float*)d_in[4];
    const float* out_b    = (const float*)d_in[5];
    const int* padding_l  = (const int*)d_in[6];
    float* out = (float*)d_out;

    char* ws = (char*)d_ws;
    ushort* y  = (ushort*)ws;                 // M*C bf16   (33.5 MB)
    ushort* wb = y + (size_t)M_DIM * C_DIM;   // 144*C bf16 (0.3 MB)
    ushort* Wb = wb + S_WG;                   // C*C bf16   (2.1 MB)

    cvt_w_kernel<<<S_CVT / 4 / 256, 256, 0, stream>>>(w_weight, glu_w, out_w, wb, Wb);
    fused_logits_conv<<<M_DIM / 16, 256, 0, stream>>>(x, wb, glu_b, padding_l, y);
    out_gemm<<<(M_DIM / 128) * (C_DIM / 128), 256, 0, stream>>>(y, Wb, out_b, out);
}

// Round 5
// 229.786 us; speedup vs baseline: 1.1386x; 1.0051x over previous
//
#include <hip/hip_runtime.h>
#include <hip/hip_bf16.h>
#include <stdint.h>

// Problem constants (DynamicConv1dTBC): T=2048 B=8 C=1024 H=16 K=7 pad_l=6
#define T_DIM 2048
#define B_DIM 8
#define C_DIM 1024
#define H_DIM 16
#define K_DIM 7
#define M_DIM (T_DIM * B_DIM)   // 16384 rows (m = t*B + b)
#define NLOG 144                // H*K (112) + 2H (32) logit columns
#define CW_STRIDE 128           // compact conv-weights row: 112 wk + 16 gates

typedef __attribute__((ext_vector_type(8))) short short8;
typedef __attribute__((ext_vector_type(4))) float floatx4;

__device__ __forceinline__ ushort f2bf(float f) {
    __hip_bfloat16 h = __float2bfloat16(f);
    return *(ushort*)&h;
}

// ---------------------------------------------------------------------------
// Kernel W: fp32 -> bf16 downcast of weights: [w_weight;glu_w] -> wb (144x1024)
// and out_w -> Wb (1024x1024).
// ---------------------------------------------------------------------------
#define S_W  ((size_t)112 * C_DIM)
#define S_G  ((size_t)32 * C_DIM)
#define S_O  ((size_t)C_DIM * C_DIM)
#define S_WG (S_W + S_G)
#define S_CVT (S_WG + S_O)                  // 1,196,032 = 4*256*1168

__global__ __launch_bounds__(256) void cvt_w_kernel(
    const float* __restrict__ w_weight, const float* __restrict__ glu_w,
    const float* __restrict__ out_w,
    ushort* __restrict__ wb, ushort* __restrict__ Wb)
{
    size_t gid = ((size_t)blockIdx.x * 256 + threadIdx.x) * 4;
    const float* src; ushort* dst; size_t off;
    if (gid < S_W)            { src = w_weight; dst = wb;       off = gid; }
    else if (gid < S_WG)      { src = glu_w;    dst = wb + S_W; off = gid - S_W; }
    else                      { src = out_w;    dst = Wb;       off = gid - S_WG; }
    float4 v = *(const float4*)(src + off);
    ushort4 o; o.x = f2bf(v.x); o.y = f2bf(v.y); o.z = f2bf(v.z); o.w = f2bf(v.w);
    *(ushort4*)(dst + off) = o;
}

// ---------------------------------------------------------------------------
// Kernel L: logits GEMM (M=16384, N=144, K=1024) + softmax/gate epilogue.
// m-tile 64 (wave w owns rows w*16..w*16+16), full N per block.
// B (wb) double-buffered in LDS via global_load_lds (32-wide K chunks);
// A (x, fp32) register-prefetched and converted to bf16 in-register.
// Epilogue: logits -> LDS, softmax over K per head + GLU gate -> cw (M,128).
// ---------------------------------------------------------------------------
__global__ __launch_bounds__(256) void logits_kernel(
    const float* __restrict__ x,       // (M, C) fp32
    const ushort* __restrict__ wb,     // (144, C) bf16
    const float* __restrict__ glu_b,   // (2H,) fp32
    float* __restrict__ cw)            // (M, 128) fp32
{
    __shared__ __align__(16) ushort Bs[2][144 * 32];  // 2 x 9216 B
    __shared__ float lsm[64][NLOG];                   // 36,864 B

    const int tid = threadIdx.x;
    const int wave = tid >> 6, lane = tid & 63;
    const int fr = lane & 15, q = lane >> 4;
    const int m0 = blockIdx.x * 64;
    const int mrow = m0 + wave * 16 + fr;

    floatx4 acc[9];
#pragma unroll
    for (int j = 0; j < 9; ++j) acc[j] = (floatx4){0.f, 0.f, 0.f, 0.f};

    const float* arow = x + (size_t)mrow * C_DIM + q * 8;

    // stage B chunk 0 (144 rows x 32 cols bf16 = 576 x 16B)
    for (int i = tid; i < 576; i += 256) {
        int r = i >> 2, ch = i & 3;
        __builtin_amdgcn_global_load_lds(
            (const __attribute__((address_space(1))) void*)(wb + (size_t)r * C_DIM + ch * 8),
            (__attribute__((address_space(3))) void*)(&Bs[0][0] + i * 8), 16, 0, 0);
    }
    float4 a0 = *(const float4*)(arow);
    float4 a1 = *(const float4*)(arow + 4);
    __syncthreads();

    for (int kc = 0; kc < 32; ++kc) {
        const int buf = kc & 1;
        if (kc < 31) {                        // stage next B chunk into other buffer
            const ushort* wsrc = wb + (kc + 1) * 32;
            for (int i = tid; i < 576; i += 256) {
                int r = i >> 2, ch = i & 3;
                __builtin_amdgcn_global_load_lds(
                    (const __attribute__((address_space(1))) void*)(wsrc + (size_t)r * C_DIM + ch * 8),
                    (__attribute__((address_space(3))) void*)(&Bs[buf ^ 1][0] + i * 8), 16, 0, 0);
            }
        }
        short8 a;
        a[0] = (short)f2bf(a0.x); a[1] = (short)f2bf(a0.y);
        a[2] = (short)f2bf(a0.z); a[3] = (short)f2bf(a0.w);
        a[4] = (short)f2bf(a1.x); a[5] = (short)f2bf(a1.y);
        a[6] = (short)f2bf(a1.z); a[7] = (short)f2bf(a1.w);
        if (kc < 31) {                        // prefetch next A
            a0 = *(const float4*)(arow + (kc + 1) * 32);
            a1 = *(const float4*)(arow + (kc + 1) * 32 + 4);
        }
#pragma unroll
        for (int j = 0; j < 9; ++j) {
            // conflict-free: lane (q,fr) -> 16B slot fr*4+q, contiguous 1 KB/wave
            short8 b = *(const short8*)(&Bs[buf][0] + ((j * 16 + fr) * 4 + q) * 8);
            acc[j] = __builtin_amdgcn_mfma_f32_16x16x32_bf16(a, b, acc[j], 0, 0, 0);
        }
        __syncthreads();
    }

    // ---- epilogue: logits -> LDS, then softmax + gate -> cw ----
#pragma unroll
    for (int j = 0; j < 9; ++j)
#pragma unroll
        for (int r = 0; r < 4; ++r)
            lsm[wave * 16 + q * 4 + r][j * 16 + fr] = acc[j][r];
    __syncthreads();

    {
        const int row = tid >> 2;             // [0,64)
        const int hbase = (tid & 3) * 4;      // 4 heads per thread
        float* crow = cw + (size_t)(m0 + row) * CW_STRIDE;
#pragma unroll
        for (int hh = 0; hh < 4; ++hh) {
            const int h = hbase + hh;
            float l[K_DIM];
            float mx = -1e30f;
#pragma unroll
            for (int k = 0; k < K_DIM; ++k) { l[k] = lsm[row][h * K_DIM + k]; mx = fmaxf(mx, l[k]); }
            float s = 0.f;
#pragma unroll
            for (int k = 0; k < K_DIM; ++k) { l[k] = __expf(l[k] - mx); s += l[k]; }
            float inv = 1.f / s;
#pragma unroll
            for (int k = 0; k < K_DIM; ++k) crow[h * K_DIM + k] = l[k] * inv;
            float ga = lsm[row][112 + 2 * h] + glu_b[2 * h];
            float gb = lsm[row][113 + 2 * h] + glu_b[2 * h + 1];
            crow[112 + h] = ga * (1.f / (1.f + __expf(-gb)));
        }
    }
}

// ---------------------------------------------------------------------------
// Kernel V: depthwise dynamic conv + gate. One wave per m-row; grid 4096
// blocks of 4 waves. XCD-swizzled so XCD k owns contiguous t-range (7-tap
// history L2-local). Lane L: channels [16L,16L+16), head = L>>2.
// ---------------------------------------------------------------------------
__global__ __launch_bounds__(256) void conv_kernel(
    const float* __restrict__ x,        // (M, C) fp32
    const float* __restrict__ cw,       // (M, 128) fp32
    const int* __restrict__ padding_l_, // scalar
    ushort* __restrict__ y)             // (M, C) bf16
{
    const int lb = (blockIdx.x & 7) * 512 + (blockIdx.x >> 3);  // XCD-contig t
    const int wave = threadIdx.x >> 6, lane = threadIdx.x & 63;
    const int m = lb * 4 + wave;
    const int t = m >> 3;
    const int pad = *padding_l_;
    const int h = lane >> 2;

    const float* crow = cw + (size_t)m * CW_STRIDE;
    float wt[K_DIM];
#pragma unroll
    for (int k = 0; k < K_DIM; ++k) wt[k] = crow[h * K_DIM + k];
    const float g = crow[112 + h];

    const int c0 = lane * 16;
    float av[16];
#pragma unroll
    for (int i = 0; i < 16; ++i) av[i] = 0.f;

#pragma unroll
    for (int k = 0; k < K_DIM; ++k) {
        int ts = t + k - pad;
        if (ts < 0 || ts >= T_DIM) continue;
        float wv = wt[k];
        const float4* xp = (const float4*)(x + ((size_t)m + 8 * (k - pad)) * C_DIM + c0);
        float4 u0 = xp[0], u1 = xp[1], u2 = xp[2], u3 = xp[3];
        av[0]  += wv * u0.x; av[1]  += wv * u0.y; av[2]  += wv * u0.z; av[3]  += wv * u0.w;
        av[4]  += wv * u1.x; av[5]  += wv * u1.y; av[6]  += wv * u1.z; av[7]  += wv * u1.w;
        av[8]  += wv * u2.x; av[9]  += wv * u2.y; av[10] += wv * u2.z; av[11] += wv * u2.w;
        av[12] += wv * u3.x; av[13] += wv * u3.y; av[14] += wv * u3.z; av[15] += wv * u3.w;
    }

    uint32_t o[8];
#pragma unroll
    for (int i = 0; i < 8; ++i)
        o[i] = (uint32_t)f2bf(av[2 * i] * g) | ((uint32_t)f2bf(av[2 * i + 1] * g) << 16);
    uint4* yr = (uint4*)(y + (size_t)m * C_DIM + c0);
    yr[0] = (uint4){o[0], o[1], o[2], o[3]};
    yr[1] = (uint4){o[4], o[5], o[6], o[7]};
}

// ---------------------------------------------------------------------------
// Kernel C: out[m,n] = sum_k y[m,k] * Wb[n,k] + out_b[n]  (bf16 MFMA, fp32 out)
// 128x128 tile, BK=64, global_load_lds staging + XOR chunk swizzle.
// Dispatch mapping: round-2 natural order (measured fastest).
// ---------------------------------------------------------------------------
__global__ __launch_bounds__(256) void out_gemm(
    const ushort* __restrict__ y,     // (M, C) bf16
    const ushort* __restrict__ Wb,    // (C, C) bf16
    const float* __restrict__ bias,   // (C,) fp32
    float* __restrict__ out)          // (M, C) fp32
{
    __shared__ __align__(16) ushort As[128 * 64];
    __shared__ __align__(16) ushort Bs[128 * 64];

    const int bn = blockIdx.x & 7;       // N/128 = 8
    const int bm = blockIdx.x >> 3;      // M/128 = 128
    const int m0 = bm * 128, n0 = bn * 128;
    const int tid = threadIdx.x;
    const int lane = tid & 63, wave = tid >> 6;
    const int wm = (wave >> 1) * 64, wn = (wave & 1) * 64;
    const int fr = lane & 15, q = lane >> 4;

    floatx4 acc[4][4];
#pragma unroll
    for (int i = 0; i < 4; ++i)
#pragma unroll
        for (int j = 0; j < 4; ++j) acc[i][j] = (floatx4){0.f, 0.f, 0.f, 0.f};

    for (int k0 = 0; k0 < C_DIM; k0 += 64) {
        __syncthreads();
#pragma unroll
        for (int j = 0; j < 4; ++j) {
            int idx = j * 256 + tid;          // LDS 16B-slot index [0,1024)
            int r = idx >> 3, cl = idx & 7;   // row, LDS chunk
            int ch = cl ^ (r & 7);            // which global chunk lands here
            const ushort* ga = y + (size_t)(m0 + r) * C_DIM + k0 + ch * 8;
            __builtin_amdgcn_global_load_lds(
                (const __attribute__((address_space(1))) void*)ga,
                (__attribute__((address_space(3))) void*)(As + idx * 8), 16, 0, 0);
            const ushort* gb = Wb + (size_t)(n0 + r) * C_DIM + k0 + ch * 8;
            __builtin_amdgcn_global_load_lds(
                (const __attribute__((address_space(1))) void*)gb,
                (__attribute__((address_space(3))) void*)(Bs + idx * 8), 16, 0, 0);
        }
        __syncthreads();

#pragma unroll
        for (int s = 0; s < 64; s += 32) {
            const int cbase = (s >> 3) + q;
            short8 a[4], b[4];
#pragma unroll
            for (int i = 0; i < 4; ++i) {
                int r = wm + i * 16 + fr;
                a[i] = *(const short8*)(As + r * 64 + ((cbase ^ (r & 7)) * 8));
            }
#pragma unroll
            for (int j = 0; j < 4; ++j) {
                int r = wn + j * 16 + fr;
                b[j] = *(const short8*)(Bs + r * 64 + ((cbase ^ (r & 7)) * 8));
            }
#pragma unroll
            for (int i = 0; i < 4; ++i)
#pragma unroll
                for (int j = 0; j < 4; ++j)
                    acc[i][j] = __builtin_amdgcn_mfma_f32_16x16x32_bf16(a[i], b[j], acc[i][j], 0, 0, 0);
        }
    }

#pragma unroll
    for (int j = 0; j < 4; ++j) {
        int n = n0 + wn + j * 16 + fr;
        float bv = bias[n];
#pragma unroll
        for (int i = 0; i < 4; ++i) {
#pragma unroll
            for (int r = 0; r < 4; ++r) {
                int m = m0 + wm + i * 16 + q * 4 + r;
                out[(size_t)m * C_DIM + n] = acc[i][j][r] + bv;
            }
        }
    }
}

// ---------------------------------------------------------------------------
extern "C" void kernel_launch(void* const* d_in, const int* in_sizes, int n_in,
                              void* d_out, int out_size, void* d_ws, size_t ws_size,
                              hipStream_t stream) {
    const float* x        = (const float*)d_in[0];
    const float* w_weight = (const float*)d_in[1];
    const float* glu_w    = (const float*)d_in[2];
    const float* glu_b    = (const float*)d_in[3];
    const float* out_w    = (const float*)d_in[4];
    const float* out_b    = (const float*)d_in[5];
    const int* padding_l  = (const int*)d_in[6];
    float* out = (float*)d_out;

    char* ws = (char*)d_ws;
    ushort* y  = (ushort*)ws;                          // M*C bf16   (33.5 MB)
    ushort* wb = y + (size_t)M_DIM * C_DIM;            // 144*C bf16 (0.3 MB)
    ushort* Wb = wb + S_WG;                            // C*C bf16   (2.1 MB)
    float* cwp = (float*)(Wb + S_O);                   // M*128 fp32 (8.4 MB)

    cvt_w_kernel<<<S_CVT / 4 / 256, 256, 0, stream>>>(w_weight, glu_w, out_w, wb, Wb);
    logits_kernel<<<M_DIM / 64, 256, 0, stream>>>(x, wb, glu_b, cwp);
    conv_kernel<<<M_DIM / 4, 256, 0, stream>>>(x, cwp, padding_l, y);
    out_gemm<<<(M_DIM / 128) * (C_DIM / 128), 256, 0, stream>>>(y, Wb, out_b, out);
}